// Round 2
// baseline (7948.264 us; speedup 1.0000x reference)
//
#include <hip/hip_runtime.h>
#include <math.h>

// Problem constants
constexpr int S_IN = 32, V_IN = 16, INVD = 16;
constexpr int S_MSG = S_IN + V_IN;           // 48
constexpr int V_MSG = S_IN + V_IN;           // 48
constexpr int NFAC  = S_MSG + V_MSG;         // 96
constexpr int S_OUT = 32, V_OUT = 16;
constexpr int OUT_PER_NODE = S_OUT + V_OUT * 3;  // 80
constexpr float ISQRT3 = 0.57735026918962576f;
constexpr float ISQ48  = 0.14433756729740643f;   // 1/sqrt(48)

__device__ __forceinline__ float silu_f(float x) {
    return x / (1.0f + __expf(-x));
}

// ---------------------------------------------------------------------------
// CSR construction
// ---------------------------------------------------------------------------
__global__ __launch_bounds__(256) void hist_kernel(
    const int* __restrict__ edst, int* __restrict__ deg, int E)
{
    int e = blockIdx.x * 256 + threadIdx.x;
    if (e < E) atomicAdd(&deg[edst[e]], 1);
}

__global__ __launch_bounds__(1024) void scan_kernel(
    const int* __restrict__ deg, int* __restrict__ offs,
    int* __restrict__ cursor, int Nn)
{
    const int T = 1024;
    int t = threadIdx.x;
    int chunk = (Nn + T - 1) / T;
    int lo = t * chunk;
    int hi = lo + chunk; if (hi > Nn) hi = Nn;
    int s = 0;
    for (int i = lo; i < hi; i++) s += deg[i];
    __shared__ int ps[T];
    ps[t] = s;
    __syncthreads();
    for (int off = 1; off < T; off <<= 1) {
        int v = (t >= off) ? ps[t - off] : 0;
        __syncthreads();
        ps[t] += v;
        __syncthreads();
    }
    int base = (t > 0) ? ps[t - 1] : 0;
    for (int i = lo; i < hi; i++) {
        offs[i] = base;
        cursor[i] = base;
        base += deg[i];
    }
    if (t == 0) offs[Nn] = ps[T - 1];
}

__global__ __launch_bounds__(256) void scatter_kernel(
    const int* __restrict__ edst, int* __restrict__ cursor,
    int* __restrict__ perm, int E)
{
    int e = blockIdx.x * 256 + threadIdx.x;
    if (e < E) {
        int pos = atomicAdd(&cursor[edst[e]], 1);
        perm[pos] = e;
    }
}

// ---------------------------------------------------------------------------
// Phase A: per-edge MLP -> 96 gate factors (scaled by cutoff), no atomics
// ---------------------------------------------------------------------------
__global__ __launch_bounds__(256) void edge_mlp_kernel(
    const float* __restrict__ ecut,
    const float* __restrict__ einv,
    const float* __restrict__ W0,
    const float* __restrict__ W1,
    const float* __restrict__ W2,
    float* __restrict__ gbuf,
    int E)
{
    int e = blockIdx.x * 256 + threadIdx.x;
    if (e >= E) return;

    float x[INVD];
    const float4* xin = reinterpret_cast<const float4*>(einv + (size_t)e * INVD);
    #pragma unroll
    for (int i = 0; i < 4; i++) {
        float4 t = xin[i];
        x[4*i+0] = t.x; x[4*i+1] = t.y; x[4*i+2] = t.z; x[4*i+3] = t.w;
    }

    constexpr float inv_s0 = 0.25f;   // 1/sqrt(16)
    constexpr float inv_s1 = 0.125f;  // 1/sqrt(64)

    float h1[64];
    #pragma unroll
    for (int j = 0; j < 64; j++) h1[j] = 0.0f;
    #pragma unroll 4
    for (int i = 0; i < INVD; i++) {
        float xi = x[i];
        #pragma unroll
        for (int j = 0; j < 64; j++)
            h1[j] = fmaf(xi, W0[i*64 + j], h1[j]);
    }
    #pragma unroll
    for (int j = 0; j < 64; j++) h1[j] = silu_f(h1[j] * inv_s0);

    float h2[64];
    #pragma unroll
    for (int j = 0; j < 64; j++) h2[j] = 0.0f;
    #pragma unroll 4
    for (int k = 0; k < 64; k++) {
        float hk = h1[k];
        #pragma unroll
        for (int j = 0; j < 64; j++)
            h2[j] = fmaf(hk, W1[k*64 + j], h2[j]);
    }
    #pragma unroll
    for (int j = 0; j < 64; j++) h2[j] = silu_f(h2[j] * inv_s1);

    float cw = ecut[e] * inv_s1;
    float* grow = gbuf + (size_t)e * NFAC;

    #pragma unroll 1
    for (int cc = 0; cc < NFAC; cc += 16) {
        float fac[16];
        #pragma unroll
        for (int c = 0; c < 16; c++) fac[c] = 0.0f;
        #pragma unroll 4
        for (int k = 0; k < 64; k++) {
            float hk = h2[k];
            #pragma unroll
            for (int c = 0; c < 16; c++)
                fac[c] = fmaf(hk, W2[k*NFAC + cc + c], fac[c]);
        }
        float4* gout = reinterpret_cast<float4*>(grow + cc);
        #pragma unroll
        for (int q = 0; q < 4; q++) {
            float4 t;
            t.x = fac[4*q+0] * cw;
            t.y = fac[4*q+1] * cw;
            t.z = fac[4*q+2] * cw;
            t.w = fac[4*q+3] * cw;
            gout[q] = t;
        }
    }
}

// ---------------------------------------------------------------------------
// Phase B: per-node gather (no atomics) + node linear, fused
// thread t < 48            -> scalar message column t
// thread t in [48,192)     -> vector column c=(t-48)/3, component i=(t-48)%3
// ---------------------------------------------------------------------------
__global__ __launch_bounds__(192) void node_gather_kernel(
    const int*   __restrict__ perm,
    const int*   __restrict__ offs,
    const int*   __restrict__ esrc,
    const float* __restrict__ esh,
    const float* __restrict__ gbuf,
    const float* __restrict__ ns,
    const float* __restrict__ nv,
    const float* __restrict__ WLs,
    const float* __restrict__ WLv,
    float* __restrict__ out,
    int Nn)
{
    int n = blockIdx.x;
    if (n >= Nn) return;
    int t = threadIdx.x;
    int beg = offs[n], end = offs[n+1];

    // decode thread -> message column
    int c_v = (t - 48) / 3;
    int i_v = (t - 48) - 3 * c_v;

    float acc = 0.0f;
    for (int p = beg; p < end; ++p) {
        int e = perm[p];
        int s = esrc[e];
        float ev0 = esh[(size_t)e*3 + 0];
        float ev1 = esh[(size_t)e*3 + 1];
        float ev2 = esh[(size_t)e*3 + 2];
        const float* grow = gbuf + (size_t)e * NFAC;
        if (t < S_MSG) {
            float gv = grow[t];
            float msgval;
            if (t < V_IN) {
                const float* vr = nv + ((size_t)s * V_IN + t) * 3;
                msgval = (vr[0]*ev0 + vr[1]*ev1 + vr[2]*ev2) * ISQRT3;
            } else {
                msgval = ns[(size_t)s * S_IN + (t - V_IN)];
            }
            acc = fmaf(msgval, gv, acc);
        } else {
            float gv = grow[S_MSG + c_v];
            float evi = (i_v == 0) ? ev0 : ((i_v == 1) ? ev1 : ev2);
            float msgval;
            if (c_v < S_IN) {
                msgval = ns[(size_t)s * S_IN + c_v] * evi;
            } else {
                msgval = nv[((size_t)s * V_IN + (c_v - S_IN)) * 3 + i_v];
            }
            acc = fmaf(msgval, gv, acc);
        }
    }

    __shared__ float accs[S_MSG + V_MSG * 3];  // 192
    accs[t] = acc;
    __syncthreads();

    if (t < OUT_PER_NODE) {
        float r = 0.0f;
        if (t < S_OUT) {
            #pragma unroll
            for (int c = 0; c < S_MSG; c++)
                r = fmaf(accs[c], WLs[c*S_OUT + t], r);
        } else {
            int u = t - S_OUT;
            int rr = u / 3;
            int ii = u - 3 * rr;
            #pragma unroll
            for (int c = 0; c < V_MSG; c++)
                r = fmaf(accs[S_MSG + c*3 + ii], WLv[c*V_OUT + rr], r);
        }
        out[(size_t)n * OUT_PER_NODE + t] = r * ISQ48;
    }
}

// ---------------------------------------------------------------------------
// Fallback (atomic) path — used only if ws_size is too small
// ---------------------------------------------------------------------------
__global__ __launch_bounds__(256) void edge_kernel_atomic(
    const int*   __restrict__ esrc,
    const int*   __restrict__ edst,
    const float* __restrict__ ecut,
    const float* __restrict__ einv,
    const float* __restrict__ ns,
    const float* __restrict__ nv,
    const float* __restrict__ esh,
    const float* __restrict__ W0,
    const float* __restrict__ W1,
    const float* __restrict__ W2,
    float* __restrict__ acc_s,
    float* __restrict__ acc_v,
    int E)
{
    int e = blockIdx.x * 256 + threadIdx.x;
    if (e >= E) return;
    float x[INVD];
    const float4* xin = reinterpret_cast<const float4*>(einv + (size_t)e * INVD);
    #pragma unroll
    for (int i = 0; i < 4; i++) {
        float4 t = xin[i];
        x[4*i+0] = t.x; x[4*i+1] = t.y; x[4*i+2] = t.z; x[4*i+3] = t.w;
    }
    constexpr float inv_s0 = 0.25f, inv_s1 = 0.125f;
    float h1[64];
    #pragma unroll
    for (int j = 0; j < 64; j++) h1[j] = 0.0f;
    #pragma unroll 4
    for (int i = 0; i < INVD; i++) {
        float xi = x[i];
        #pragma unroll
        for (int j = 0; j < 64; j++) h1[j] = fmaf(xi, W0[i*64 + j], h1[j]);
    }
    #pragma unroll
    for (int j = 0; j < 64; j++) h1[j] = silu_f(h1[j] * inv_s0);
    float h2[64];
    #pragma unroll
    for (int j = 0; j < 64; j++) h2[j] = 0.0f;
    #pragma unroll 4
    for (int k = 0; k < 64; k++) {
        float hk = h1[k];
        #pragma unroll
        for (int j = 0; j < 64; j++) h2[j] = fmaf(hk, W1[k*64 + j], h2[j]);
    }
    #pragma unroll
    for (int j = 0; j < 64; j++) h2[j] = silu_f(h2[j] * inv_s1);
    int s = esrc[e];
    int d = edst[e];
    float cw  = ecut[e];
    float ev0 = esh[(size_t)e*3+0], ev1 = esh[(size_t)e*3+1], ev2 = esh[(size_t)e*3+2];
    const float* nsrow = ns + (size_t)s * S_IN;
    const float* nvrow = nv + (size_t)s * (V_IN*3);
    float* accs = acc_s + (size_t)d * S_MSG;
    float* accv = acc_v + (size_t)d * (V_MSG*3);
    #pragma unroll 1
    for (int cc = 0; cc < NFAC; cc += 16) {
        float fac[16];
        #pragma unroll
        for (int c = 0; c < 16; c++) fac[c] = 0.0f;
        #pragma unroll 4
        for (int k = 0; k < 64; k++) {
            float hk = h2[k];
            #pragma unroll
            for (int c = 0; c < 16; c++) fac[c] = fmaf(hk, W2[k*NFAC + cc + c], fac[c]);
        }
        #pragma unroll
        for (int c = 0; c < 16; c++) {
            int col = cc + c;
            float g = fac[c] * inv_s1 * cw;
            if (col < S_MSG) {
                float val;
                if (col < V_IN) {
                    float a0 = nvrow[3*col+0], a1 = nvrow[3*col+1], a2 = nvrow[3*col+2];
                    val = (a0*ev0 + a1*ev1 + a2*ev2) * ISQRT3;
                } else val = nsrow[col - V_IN];
                atomicAdd(&accs[col], val * g);
            } else {
                int r = col - S_MSG;
                if (r < S_IN) {
                    float b = nsrow[r] * g;
                    atomicAdd(&accv[3*r+0], b*ev0);
                    atomicAdd(&accv[3*r+1], b*ev1);
                    atomicAdd(&accv[3*r+2], b*ev2);
                } else {
                    int q = r - S_IN;
                    atomicAdd(&accv[3*r+0], nvrow[3*q+0] * g);
                    atomicAdd(&accv[3*r+1], nvrow[3*q+1] * g);
                    atomicAdd(&accv[3*r+2], nvrow[3*q+2] * g);
                }
            }
        }
    }
}

__global__ __launch_bounds__(256) void node_kernel_atomic(
    const float* __restrict__ acc_s,
    const float* __restrict__ acc_v,
    const float* __restrict__ WLs,
    const float* __restrict__ WLv,
    float* __restrict__ out,
    int Nn)
{
    int idx = blockIdx.x * 256 + threadIdx.x;
    if (idx >= Nn * OUT_PER_NODE) return;
    int n = idx / OUT_PER_NODE;
    int o = idx - n * OUT_PER_NODE;
    float accum = 0.0f;
    if (o < S_OUT) {
        const float* row = acc_s + (size_t)n * S_MSG;
        #pragma unroll
        for (int c = 0; c < S_MSG; c++) accum = fmaf(row[c], WLs[c*S_OUT + o], accum);
    } else {
        int t = o - S_OUT;
        int r = t / 3;
        int i = t - 3*r;
        const float* row = acc_v + (size_t)n * (V_MSG*3);
        #pragma unroll
        for (int c = 0; c < V_MSG; c++) accum = fmaf(row[c*3 + i], WLv[c*V_OUT + r], accum);
    }
    out[idx] = accum * ISQ48;
}

// ---------------------------------------------------------------------------
extern "C" void kernel_launch(void* const* d_in, const int* in_sizes, int n_in,
                              void* d_out, int out_size, void* d_ws, size_t ws_size,
                              hipStream_t stream) {
    const int*   esrc = (const int*)  d_in[0];
    const int*   edst = (const int*)  d_in[1];
    const float* ecut = (const float*)d_in[2];
    const float* einv = (const float*)d_in[3];
    const float* ns   = (const float*)d_in[4];
    const float* nv   = (const float*)d_in[5];
    const float* esh  = (const float*)d_in[6];
    const float* W0   = (const float*)d_in[7];
    const float* W1   = (const float*)d_in[8];
    const float* W2   = (const float*)d_in[9];
    const float* WLs  = (const float*)d_in[10];
    const float* WLv  = (const float*)d_in[11];
    float* out = (float*)d_out;

    const int E  = in_sizes[0];
    const int Nn = in_sizes[4] / S_IN;

    // workspace layout for fast path
    size_t int_count = (size_t)(3 * Nn + 1 + E);
    size_t g_off = (int_count * sizeof(int) + 255) & ~(size_t)255;
    size_t need  = g_off + (size_t)E * NFAC * sizeof(float);

    int eblocks = (E + 255) / 256;

    if (ws_size >= need) {
        int*   deg    = (int*)d_ws;
        int*   offs   = deg + Nn;          // Nn+1
        int*   cursor = offs + Nn + 1;     // Nn
        int*   perm   = cursor + Nn;       // E
        float* gbuf   = (float*)((char*)d_ws + g_off);

        hipMemsetAsync(deg, 0, (size_t)Nn * sizeof(int), stream);
        hist_kernel<<<eblocks, 256, 0, stream>>>(edst, deg, E);
        scan_kernel<<<1, 1024, 0, stream>>>(deg, offs, cursor, Nn);
        scatter_kernel<<<eblocks, 256, 0, stream>>>(edst, cursor, perm, E);
        edge_mlp_kernel<<<eblocks, 256, 0, stream>>>(ecut, einv, W0, W1, W2, gbuf, E);
        node_gather_kernel<<<Nn, 192, 0, stream>>>(perm, offs, esrc, esh, gbuf,
                                                   ns, nv, WLs, WLv, out, Nn);
    } else {
        // fallback: proven atomic path
        float* acc_s = (float*)d_ws;                       // N x 48
        float* acc_v = acc_s + (size_t)Nn * S_MSG;         // N x 48 x 3
        size_t acc_bytes = (size_t)Nn * (S_MSG + V_MSG*3) * sizeof(float);
        hipMemsetAsync(d_ws, 0, acc_bytes, stream);
        edge_kernel_atomic<<<eblocks, 256, 0, stream>>>(esrc, edst, ecut, einv, ns, nv, esh,
                                                        W0, W1, W2, acc_s, acc_v, E);
        int nthreads = Nn * OUT_PER_NODE;
        int nblocks = (nthreads + 255) / 256;
        node_kernel_atomic<<<nblocks, 256, 0, stream>>>(acc_s, acc_v, WLs, WLv, out, Nn);
    }
}

// Round 3
// 1512.330 us; speedup vs baseline: 5.2556x; 5.2556x over previous
//
#include <hip/hip_runtime.h>
#include <math.h>

// Problem constants
constexpr int S_IN = 32, V_IN = 16, INVD = 16;
constexpr int S_MSG = S_IN + V_IN;           // 48
constexpr int V_MSG = S_IN + V_IN;           // 48
constexpr int NFAC  = S_MSG + V_MSG;         // 96
constexpr int S_OUT = 32, V_OUT = 16;
constexpr int OUT_PER_NODE = S_OUT + V_OUT * 3;  // 80
constexpr int ACC_W = S_MSG + V_MSG * 3;         // 192 accumulator cols per node
constexpr float ISQRT3 = 0.57735026918962576f;
constexpr float ISQ48  = 0.14433756729740643f;   // 1/sqrt(48)

__device__ __forceinline__ float silu_f(float x) {
    return x / (1.0f + __expf(-x));
}

// ---------------------------------------------------------------------------
// CSR construction
// ---------------------------------------------------------------------------
__global__ __launch_bounds__(256) void hist_kernel(
    const int* __restrict__ edst, int* __restrict__ deg, int E)
{
    int e = blockIdx.x * 256 + threadIdx.x;
    if (e < E) atomicAdd(&deg[edst[e]], 1);
}

__global__ __launch_bounds__(1024) void scan_kernel(
    const int* __restrict__ deg, int* __restrict__ offs,
    int* __restrict__ cursor, int Nn)
{
    const int T = 1024;
    int t = threadIdx.x;
    int chunk = (Nn + T - 1) / T;
    int lo = t * chunk;
    int hi = lo + chunk; if (hi > Nn) hi = Nn;
    int s = 0;
    for (int i = lo; i < hi; i++) s += deg[i];
    __shared__ int ps[T];
    ps[t] = s;
    __syncthreads();
    for (int off = 1; off < T; off <<= 1) {
        int v = (t >= off) ? ps[t - off] : 0;
        __syncthreads();
        ps[t] += v;
        __syncthreads();
    }
    int base = (t > 0) ? ps[t - 1] : 0;
    for (int i = lo; i < hi; i++) {
        offs[i] = base;
        cursor[i] = base;
        base += deg[i];
    }
    if (t == 0) offs[Nn] = ps[T - 1];
}

__global__ __launch_bounds__(256) void scatter_kernel(
    const int* __restrict__ edst, int* __restrict__ cursor,
    int* __restrict__ perm, int E)
{
    int e = blockIdx.x * 256 + threadIdx.x;
    if (e < E) {
        int pos = atomicAdd(&cursor[edst[e]], 1);
        perm[pos] = e;
    }
}

// ---------------------------------------------------------------------------
// Phase A (chunked): per-edge MLP -> 96 gates, written in PERMUTED order
// ---------------------------------------------------------------------------
__global__ __launch_bounds__(256) void edge_mlp_chunk(
    const int*   __restrict__ perm,
    const float* __restrict__ ecut,
    const float* __restrict__ einv,
    const float* __restrict__ W0,
    const float* __restrict__ W1,
    const float* __restrict__ W2,
    float* __restrict__ gbuf,
    int p0, int p1)
{
    int p = p0 + blockIdx.x * 256 + threadIdx.x;
    if (p >= p1) return;
    int e = perm[p];

    float x[INVD];
    const float4* xin = reinterpret_cast<const float4*>(einv + (size_t)e * INVD);
    #pragma unroll
    for (int i = 0; i < 4; i++) {
        float4 t = xin[i];
        x[4*i+0] = t.x; x[4*i+1] = t.y; x[4*i+2] = t.z; x[4*i+3] = t.w;
    }

    constexpr float inv_s0 = 0.25f;   // 1/sqrt(16)
    constexpr float inv_s1 = 0.125f;  // 1/sqrt(64)

    float h1[64];
    #pragma unroll
    for (int j = 0; j < 64; j++) h1[j] = 0.0f;
    #pragma unroll 4
    for (int i = 0; i < INVD; i++) {
        float xi = x[i];
        #pragma unroll
        for (int j = 0; j < 64; j++)
            h1[j] = fmaf(xi, W0[i*64 + j], h1[j]);
    }
    #pragma unroll
    for (int j = 0; j < 64; j++) h1[j] = silu_f(h1[j] * inv_s0);

    float h2[64];
    #pragma unroll
    for (int j = 0; j < 64; j++) h2[j] = 0.0f;
    #pragma unroll 4
    for (int k = 0; k < 64; k++) {
        float hk = h1[k];
        #pragma unroll
        for (int j = 0; j < 64; j++)
            h2[j] = fmaf(hk, W1[k*64 + j], h2[j]);
    }
    #pragma unroll
    for (int j = 0; j < 64; j++) h2[j] = silu_f(h2[j] * inv_s1);

    float cw = ecut[e] * inv_s1;
    float* grow = gbuf + (size_t)(p - p0) * NFAC;

    #pragma unroll 1
    for (int cc = 0; cc < NFAC; cc += 16) {
        float fac[16];
        #pragma unroll
        for (int c = 0; c < 16; c++) fac[c] = 0.0f;
        #pragma unroll 4
        for (int k = 0; k < 64; k++) {
            float hk = h2[k];
            #pragma unroll
            for (int c = 0; c < 16; c++)
                fac[c] = fmaf(hk, W2[k*NFAC + cc + c], fac[c]);
        }
        float4* gout = reinterpret_cast<float4*>(grow + cc);
        #pragma unroll
        for (int q = 0; q < 4; q++) {
            float4 t;
            t.x = fac[4*q+0] * cw;
            t.y = fac[4*q+1] * cw;
            t.z = fac[4*q+2] * cw;
            t.w = fac[4*q+3] * cw;
            gout[q] = t;
        }
    }
}

// ---------------------------------------------------------------------------
// Phase B (chunked): per-node gather over permuted range [p0,p1), accumulate
// into acc[n][192]. Persistent grid; node-stride; fast skip outside chunk.
// thread t < 48        -> scalar message column t
// t in [48,192)        -> vector column c=(t-48)/3, component i=(t-48)%3
// ---------------------------------------------------------------------------
__global__ __launch_bounds__(192) void gather_chunk(
    const int*   __restrict__ perm,
    const int*   __restrict__ offs,
    const int*   __restrict__ esrc,
    const float* __restrict__ esh,
    const float* __restrict__ gbuf,
    const float* __restrict__ ns,
    const float* __restrict__ nv,
    float* __restrict__ acc,
    int Nn, int p0, int p1)
{
    int t = threadIdx.x;
    int c_v = (t - 48) / 3;
    int i_v = (t - 48) - 3 * c_v;

    for (int n = blockIdx.x; n < Nn; n += gridDim.x) {
        int beg = offs[n], end = offs[n + 1];
        int lo = beg > p0 ? beg : p0;
        int hi = end < p1 ? end : p1;
        if (lo >= hi) continue;

        float a = 0.0f;
        for (int p = lo; p < hi; ++p) {
            int e = perm[p];
            int s = esrc[e];
            float ev0 = esh[(size_t)e*3 + 0];
            float ev1 = esh[(size_t)e*3 + 1];
            float ev2 = esh[(size_t)e*3 + 2];
            const float* grow = gbuf + (size_t)(p - p0) * NFAC;
            if (t < S_MSG) {
                float gv = grow[t];
                float msgval;
                if (t < V_IN) {
                    const float* vr = nv + ((size_t)s * V_IN + t) * 3;
                    msgval = (vr[0]*ev0 + vr[1]*ev1 + vr[2]*ev2) * ISQRT3;
                } else {
                    msgval = ns[(size_t)s * S_IN + (t - V_IN)];
                }
                a = fmaf(msgval, gv, a);
            } else {
                float gv = grow[S_MSG + c_v];
                float evi = (i_v == 0) ? ev0 : ((i_v == 1) ? ev1 : ev2);
                float msgval;
                if (c_v < S_IN) {
                    msgval = ns[(size_t)s * S_IN + c_v] * evi;
                } else {
                    msgval = nv[((size_t)s * V_IN + (c_v - S_IN)) * 3 + i_v];
                }
                a = fmaf(msgval, gv, a);
            }
        }
        float* arow = acc + (size_t)n * ACC_W;
        arow[t] += a;   // exclusive owner of node n within this launch
    }
}

// ---------------------------------------------------------------------------
// Final: node linear from acc[n][192] -> out[n][80]
// ---------------------------------------------------------------------------
__global__ __launch_bounds__(256) void node_linear_kernel(
    const float* __restrict__ acc,
    const float* __restrict__ WLs,
    const float* __restrict__ WLv,
    float* __restrict__ out,
    int Nn)
{
    int idx = blockIdx.x * 256 + threadIdx.x;
    if (idx >= Nn * OUT_PER_NODE) return;
    int n = idx / OUT_PER_NODE;
    int o = idx - n * OUT_PER_NODE;
    const float* arow = acc + (size_t)n * ACC_W;
    float r = 0.0f;
    if (o < S_OUT) {
        #pragma unroll
        for (int c = 0; c < S_MSG; c++)
            r = fmaf(arow[c], WLs[c*S_OUT + o], r);
    } else {
        int u = o - S_OUT;
        int rr = u / 3;
        int ii = u - 3 * rr;
        #pragma unroll
        for (int c = 0; c < V_MSG; c++)
            r = fmaf(arow[S_MSG + c*3 + ii], WLv[c*V_OUT + rr], r);
    }
    out[idx] = r * ISQ48;
}

// ---------------------------------------------------------------------------
// Fallback (atomic) path — only if workspace is tiny
// ---------------------------------------------------------------------------
__global__ __launch_bounds__(256) void edge_kernel_atomic(
    const int*   __restrict__ esrc,
    const int*   __restrict__ edst,
    const float* __restrict__ ecut,
    const float* __restrict__ einv,
    const float* __restrict__ ns,
    const float* __restrict__ nv,
    const float* __restrict__ esh,
    const float* __restrict__ W0,
    const float* __restrict__ W1,
    const float* __restrict__ W2,
    float* __restrict__ acc,
    int E)
{
    int e = blockIdx.x * 256 + threadIdx.x;
    if (e >= E) return;
    float x[INVD];
    const float4* xin = reinterpret_cast<const float4*>(einv + (size_t)e * INVD);
    #pragma unroll
    for (int i = 0; i < 4; i++) {
        float4 t = xin[i];
        x[4*i+0] = t.x; x[4*i+1] = t.y; x[4*i+2] = t.z; x[4*i+3] = t.w;
    }
    constexpr float inv_s0 = 0.25f, inv_s1 = 0.125f;
    float h1[64];
    #pragma unroll
    for (int j = 0; j < 64; j++) h1[j] = 0.0f;
    #pragma unroll 4
    for (int i = 0; i < INVD; i++) {
        float xi = x[i];
        #pragma unroll
        for (int j = 0; j < 64; j++) h1[j] = fmaf(xi, W0[i*64 + j], h1[j]);
    }
    #pragma unroll
    for (int j = 0; j < 64; j++) h1[j] = silu_f(h1[j] * inv_s0);
    float h2[64];
    #pragma unroll
    for (int j = 0; j < 64; j++) h2[j] = 0.0f;
    #pragma unroll 4
    for (int k = 0; k < 64; k++) {
        float hk = h1[k];
        #pragma unroll
        for (int j = 0; j < 64; j++) h2[j] = fmaf(hk, W1[k*64 + j], h2[j]);
    }
    #pragma unroll
    for (int j = 0; j < 64; j++) h2[j] = silu_f(h2[j] * inv_s1);
    int s = esrc[e];
    int d = edst[e];
    float cw  = ecut[e];
    float ev0 = esh[(size_t)e*3+0], ev1 = esh[(size_t)e*3+1], ev2 = esh[(size_t)e*3+2];
    const float* nsrow = ns + (size_t)s * S_IN;
    const float* nvrow = nv + (size_t)s * (V_IN*3);
    float* arow = acc + (size_t)d * ACC_W;
    #pragma unroll 1
    for (int cc = 0; cc < NFAC; cc += 16) {
        float fac[16];
        #pragma unroll
        for (int c = 0; c < 16; c++) fac[c] = 0.0f;
        #pragma unroll 4
        for (int k = 0; k < 64; k++) {
            float hk = h2[k];
            #pragma unroll
            for (int c = 0; c < 16; c++) fac[c] = fmaf(hk, W2[k*NFAC + cc + c], fac[c]);
        }
        #pragma unroll
        for (int c = 0; c < 16; c++) {
            int col = cc + c;
            float g = fac[c] * inv_s1 * cw;
            if (col < S_MSG) {
                float val;
                if (col < V_IN) {
                    float a0 = nvrow[3*col+0], a1 = nvrow[3*col+1], a2 = nvrow[3*col+2];
                    val = (a0*ev0 + a1*ev1 + a2*ev2) * ISQRT3;
                } else val = nsrow[col - V_IN];
                atomicAdd(&arow[col], val * g);
            } else {
                int r = col - S_MSG;
                if (r < S_IN) {
                    float b = nsrow[r] * g;
                    atomicAdd(&arow[S_MSG + 3*r+0], b*ev0);
                    atomicAdd(&arow[S_MSG + 3*r+1], b*ev1);
                    atomicAdd(&arow[S_MSG + 3*r+2], b*ev2);
                } else {
                    int q = r - S_IN;
                    atomicAdd(&arow[S_MSG + 3*r+0], nvrow[3*q+0] * g);
                    atomicAdd(&arow[S_MSG + 3*r+1], nvrow[3*q+1] * g);
                    atomicAdd(&arow[S_MSG + 3*r+2], nvrow[3*q+2] * g);
                }
            }
        }
    }
}

// ---------------------------------------------------------------------------
extern "C" void kernel_launch(void* const* d_in, const int* in_sizes, int n_in,
                              void* d_out, int out_size, void* d_ws, size_t ws_size,
                              hipStream_t stream) {
    const int*   esrc = (const int*)  d_in[0];
    const int*   edst = (const int*)  d_in[1];
    const float* ecut = (const float*)d_in[2];
    const float* einv = (const float*)d_in[3];
    const float* ns   = (const float*)d_in[4];
    const float* nv   = (const float*)d_in[5];
    const float* esh  = (const float*)d_in[6];
    const float* W0   = (const float*)d_in[7];
    const float* W1   = (const float*)d_in[8];
    const float* W2   = (const float*)d_in[9];
    const float* WLs  = (const float*)d_in[10];
    const float* WLv  = (const float*)d_in[11];
    float* out = (float*)d_out;

    const int E  = in_sizes[0];
    const int Nn = in_sizes[4] / S_IN;

    size_t int_bytes = (((size_t)(3 * Nn + 1 + E)) * sizeof(int) + 255) & ~(size_t)255;
    size_t acc_bytes = (size_t)Nn * ACC_W * sizeof(float);

    int eblocks = (E + 255) / 256;
    int nlin_blocks = (Nn * OUT_PER_NODE + 255) / 256;

    // fast path requires CSR ints + acc + at least ~8 MB of gate buffer
    if (ws_size >= int_bytes + acc_bytes + ((size_t)8 << 20)) {
        int*   deg    = (int*)d_ws;
        int*   offs   = deg + Nn;          // Nn+1
        int*   cursor = offs + Nn + 1;     // Nn
        int*   perm   = cursor + Nn;       // E
        float* acc    = (float*)((char*)d_ws + int_bytes);
        float* gbuf   = (float*)((char*)d_ws + int_bytes + acc_bytes);

        size_t gbuf_avail = ws_size - int_bytes - acc_bytes;
        int chunkE = (int)(gbuf_avail / ((size_t)NFAC * sizeof(float)));
        if (chunkE > E) chunkE = E;

        hipMemsetAsync(deg, 0, (size_t)Nn * sizeof(int), stream);
        hipMemsetAsync(acc, 0, acc_bytes, stream);
        hist_kernel<<<eblocks, 256, 0, stream>>>(edst, deg, E);
        scan_kernel<<<1, 1024, 0, stream>>>(deg, offs, cursor, Nn);
        scatter_kernel<<<eblocks, 256, 0, stream>>>(edst, cursor, perm, E);

        for (int p0 = 0; p0 < E; p0 += chunkE) {
            int p1 = p0 + chunkE; if (p1 > E) p1 = E;
            int cblocks = (p1 - p0 + 255) / 256;
            edge_mlp_chunk<<<cblocks, 256, 0, stream>>>(perm, ecut, einv,
                                                        W0, W1, W2, gbuf, p0, p1);
            gather_chunk<<<2048, 192, 0, stream>>>(perm, offs, esrc, esh, gbuf,
                                                   ns, nv, acc, Nn, p0, p1);
        }
        node_linear_kernel<<<nlin_blocks, 256, 0, stream>>>(acc, WLs, WLv, out, Nn);
    } else {
        // fallback: atomic path (needs only the 38.4 MB accumulator)
        float* acc = (float*)d_ws;   // N x 192
        hipMemsetAsync(acc, 0, acc_bytes, stream);
        edge_kernel_atomic<<<eblocks, 256, 0, stream>>>(esrc, edst, ecut, einv, ns, nv, esh,
                                                        W0, W1, W2, acc, E);
        node_linear_kernel<<<nlin_blocks, 256, 0, stream>>>(acc, WLs, WLv, out, Nn);
    }
}

// Round 4
// 951.736 us; speedup vs baseline: 8.3513x; 1.5890x over previous
//
#include <hip/hip_runtime.h>
#include <hip/hip_fp16.h>
#include <math.h>

// Problem constants
constexpr int S_IN = 32, V_IN = 16, INVD = 16;
constexpr int S_MSG = S_IN + V_IN;           // 48
constexpr int V_MSG = S_IN + V_IN;           // 48
constexpr int NFAC  = S_MSG + V_MSG;         // 96
constexpr int S_OUT = 32, V_OUT = 16;
constexpr int OUT_PER_NODE = S_OUT + V_OUT * 3;  // 80
constexpr float ISQRT3 = 0.57735026918962576f;
constexpr float ISQ48  = 0.14433756729740643f;   // 1/sqrt(48)

__device__ __forceinline__ float silu_f(float x) {
    return x / (1.0f + __expf(-x));
}

// ---------------------------------------------------------------------------
// CSR construction
// ---------------------------------------------------------------------------
__global__ __launch_bounds__(256) void hist_kernel(
    const int* __restrict__ edst, int* __restrict__ deg, int E)
{
    int e = blockIdx.x * 256 + threadIdx.x;
    if (e < E) atomicAdd(&deg[edst[e]], 1);
}

__global__ __launch_bounds__(1024) void scan_kernel(
    const int* __restrict__ deg, int* __restrict__ offs,
    int* __restrict__ cursor, int Nn)
{
    const int T = 1024;
    int t = threadIdx.x;
    int chunk = (Nn + T - 1) / T;
    int lo = t * chunk;
    int hi = lo + chunk; if (hi > Nn) hi = Nn;
    int s = 0;
    for (int i = lo; i < hi; i++) s += deg[i];
    __shared__ int ps[T];
    ps[t] = s;
    __syncthreads();
    for (int off = 1; off < T; off <<= 1) {
        int v = (t >= off) ? ps[t - off] : 0;
        __syncthreads();
        ps[t] += v;
        __syncthreads();
    }
    int base = (t > 0) ? ps[t - 1] : 0;
    for (int i = lo; i < hi; i++) {
        offs[i] = base;
        cursor[i] = base;
        base += deg[i];
    }
    if (t == 0) offs[Nn] = ps[T - 1];
}

__global__ __launch_bounds__(256) void scatter_kernel(
    const int* __restrict__ edst, int* __restrict__ cursor,
    int* __restrict__ perm, int E)
{
    int e = blockIdx.x * 256 + threadIdx.x;
    if (e < E) {
        int pos = atomicAdd(&cursor[edst[e]], 1);
        perm[pos] = e;
    }
}

// ---------------------------------------------------------------------------
// Fused edge kernel: MLP -> gates -> message -> per-edge WL -> 80-float
// contribution.  ATOMIC=0: write fp16 row to gbuf at permuted position p.
// ATOMIC=1: atomicAdd fp32 into out (fallback, no workspace needed).
// ---------------------------------------------------------------------------
template<int ATOMIC>
__global__ __launch_bounds__(256) void edge_fused(
    const int*   __restrict__ perm,
    const int*   __restrict__ esrc,
    const int*   __restrict__ edst,
    const float* __restrict__ ecut,
    const float* __restrict__ einv,
    const float* __restrict__ ns,
    const float* __restrict__ nv,
    const float* __restrict__ esh,
    const float* __restrict__ W0,
    const float* __restrict__ W1,
    const float* __restrict__ W2,
    const float* __restrict__ WLs,
    const float* __restrict__ WLv,
    __half* __restrict__ gbuf,
    float*  __restrict__ out,
    int p0, int p1)
{
    int p = p0 + blockIdx.x * 256 + threadIdx.x;
    if (p >= p1) return;
    int e = ATOMIC ? p : perm[p];

    // ---- edge invariants ----
    float x[INVD];
    const float4* xin = reinterpret_cast<const float4*>(einv + (size_t)e * INVD);
    #pragma unroll
    for (int i = 0; i < 4; i++) {
        float4 t = xin[i];
        x[4*i+0] = t.x; x[4*i+1] = t.y; x[4*i+2] = t.z; x[4*i+3] = t.w;
    }

    constexpr float inv_s0 = 0.25f;   // 1/sqrt(16)
    constexpr float inv_s1 = 0.125f;  // 1/sqrt(64)

    // ---- layer 1: 16 -> 64 ----
    float h1[64];
    #pragma unroll
    for (int j = 0; j < 64; j++) h1[j] = 0.0f;
    #pragma unroll 4
    for (int i = 0; i < INVD; i++) {
        float xi = x[i];
        #pragma unroll
        for (int j = 0; j < 64; j++)
            h1[j] = fmaf(xi, W0[i*64 + j], h1[j]);
    }
    #pragma unroll
    for (int j = 0; j < 64; j++) h1[j] = silu_f(h1[j] * inv_s0);

    // ---- layer 2: 64 -> 64 ----
    float h2[64];
    #pragma unroll
    for (int j = 0; j < 64; j++) h2[j] = 0.0f;
    #pragma unroll 4
    for (int k = 0; k < 64; k++) {
        float hk = h1[k];
        #pragma unroll
        for (int j = 0; j < 64; j++)
            h2[j] = fmaf(hk, W1[k*64 + j], h2[j]);
    }
    #pragma unroll
    for (int j = 0; j < 64; j++) h2[j] = silu_f(h2[j] * inv_s1);

    // ---- layer 3: 64 -> 96 (all gates) ----
    float fac[NFAC];
    #pragma unroll
    for (int c = 0; c < NFAC; c++) fac[c] = 0.0f;
    #pragma unroll 4
    for (int k = 0; k < 64; k++) {
        float hk = h2[k];
        #pragma unroll
        for (int c = 0; c < NFAC; c++)
            fac[c] = fmaf(hk, W2[k*NFAC + c], fac[c]);
    }

    // fold cutoff, 1/sqrt(64), 1/sqrt(48) into the gates; 1/sqrt(3) into c<16
    float K = ecut[e] * inv_s1 * ISQ48;
    #pragma unroll
    for (int c = 0; c < NFAC; c++) fac[c] *= K;
    #pragma unroll
    for (int c = 0; c < 16; c++) fac[c] *= ISQRT3;

    // ---- per-edge data ----
    int s = esrc[e];
    float ev0 = esh[(size_t)e*3 + 0];
    float ev1 = esh[(size_t)e*3 + 1];
    float ev2 = esh[(size_t)e*3 + 2];

    float nsr[S_IN];
    const float4* nsl = reinterpret_cast<const float4*>(ns + (size_t)s * S_IN);
    #pragma unroll
    for (int i = 0; i < 8; i++) {
        float4 t = nsl[i];
        nsr[4*i+0] = t.x; nsr[4*i+1] = t.y; nsr[4*i+2] = t.z; nsr[4*i+3] = t.w;
    }
    float nvr[V_IN * 3];
    const float4* nvl = reinterpret_cast<const float4*>(nv + (size_t)s * (V_IN*3));
    #pragma unroll
    for (int i = 0; i < 12; i++) {
        float4 t = nvl[i];
        nvr[4*i+0] = t.x; nvr[4*i+1] = t.y; nvr[4*i+2] = t.z; nvr[4*i+3] = t.w;
    }

    // ---- scalar outputs: ys[o] = sum_c msg_s[c]*g[c]*WLs[c][o] ----
    float ys[S_OUT];
    #pragma unroll
    for (int o = 0; o < S_OUT; o++) ys[o] = 0.0f;
    #pragma unroll
    for (int c = 0; c < V_IN; c++) {     // tp_s part (ISQRT3 folded)
        float m = (nvr[3*c+0]*ev0 + nvr[3*c+1]*ev1 + nvr[3*c+2]*ev2) * fac[c];
        #pragma unroll
        for (int o = 0; o < S_OUT; o++)
            ys[o] = fmaf(m, WLs[c*S_OUT + o], ys[o]);
    }
    #pragma unroll
    for (int c = 0; c < S_IN; c++) {     // src_s part
        float m = nsr[c] * fac[V_IN + c];
        #pragma unroll
        for (int o = 0; o < S_OUT; o++)
            ys[o] = fmaf(m, WLs[(V_IN + c)*S_OUT + o], ys[o]);
    }

    // ---- vector outputs: yv[o][i] = sum_c msg_v[c][i]*g[48+c]*WLv[c][o] ----
    float yv[V_OUT * 3];
    #pragma unroll
    for (int q = 0; q < V_OUT*3; q++) yv[q] = 0.0f;
    #pragma unroll
    for (int c = 0; c < S_IN; c++) {     // tp_v part: ns[c]*ev
        float m  = nsr[c] * fac[S_MSG + c];
        float m0 = m * ev0, m1 = m * ev1, m2 = m * ev2;
        #pragma unroll
        for (int o = 0; o < V_OUT; o++) {
            float w = WLv[c*V_OUT + o];
            yv[3*o+0] = fmaf(w, m0, yv[3*o+0]);
            yv[3*o+1] = fmaf(w, m1, yv[3*o+1]);
            yv[3*o+2] = fmaf(w, m2, yv[3*o+2]);
        }
    }
    #pragma unroll
    for (int c = 0; c < V_IN; c++) {     // src_v part
        float g  = fac[S_MSG + S_IN + c];
        float v0 = nvr[3*c+0] * g, v1 = nvr[3*c+1] * g, v2 = nvr[3*c+2] * g;
        #pragma unroll
        for (int o = 0; o < V_OUT; o++) {
            float w = WLv[(S_IN + c)*V_OUT + o];
            yv[3*o+0] = fmaf(w, v0, yv[3*o+0]);
            yv[3*o+1] = fmaf(w, v1, yv[3*o+1]);
            yv[3*o+2] = fmaf(w, v2, yv[3*o+2]);
        }
    }

    if (ATOMIC) {
        int d = edst[e];
        float* orow = out + (size_t)d * OUT_PER_NODE;
        #pragma unroll
        for (int o = 0; o < S_OUT; o++) atomicAdd(&orow[o], ys[o]);
        #pragma unroll
        for (int q = 0; q < V_OUT*3; q++) atomicAdd(&orow[S_OUT + q], yv[q]);
    } else {
        // pack 80 fp16 -> 10 x uint4 (rows are 160B, 16B-aligned)
        unsigned int w32[40];
        #pragma unroll
        for (int q = 0; q < 16; q++) {
            __half2 hh = __floats2half2_rn(ys[2*q], ys[2*q+1]);
            w32[q] = *reinterpret_cast<unsigned int*>(&hh);
        }
        #pragma unroll
        for (int q = 0; q < 24; q++) {
            __half2 hh = __floats2half2_rn(yv[2*q], yv[2*q+1]);
            w32[16+q] = *reinterpret_cast<unsigned int*>(&hh);
        }
        uint4* dst = reinterpret_cast<uint4*>(gbuf + (size_t)(p - p0) * OUT_PER_NODE);
        #pragma unroll
        for (int q = 0; q < 10; q++)
            dst[q] = make_uint4(w32[4*q+0], w32[4*q+1], w32[4*q+2], w32[4*q+3]);
    }
}

// ---------------------------------------------------------------------------
// Gather: one wave per node, sum fp16 rows over the node's permuted range.
// Addresses depend only on p -> fully prefetchable, no dependent loads.
// ---------------------------------------------------------------------------
__global__ __launch_bounds__(256) void gather_sum(
    const int*   __restrict__ offs,
    const __half* __restrict__ gbuf,
    float* __restrict__ out,
    int Nn, int p0, int p1)
{
    int wid = (blockIdx.x * 256 + threadIdx.x) >> 6;   // node = global wave id
    int l = threadIdx.x & 63;
    if (wid >= Nn) return;
    int beg = offs[wid], end = offs[wid + 1];
    int lo = beg > p0 ? beg : p0;
    int hi = end < p1 ? end : p1;
    if (lo >= hi) return;

    float a0 = 0.0f, a1 = 0.0f;
    const __half* row = gbuf + (size_t)(lo - p0) * OUT_PER_NODE;
    #pragma unroll 4
    for (int p = lo; p < hi; ++p, row += OUT_PER_NODE) {
        a0 += __half2float(row[l]);
        if (l < 16) a1 += __half2float(row[64 + l]);
    }
    float* orow = out + (size_t)wid * OUT_PER_NODE;
    orow[l] += a0;
    if (l < 16) orow[64 + l] += a1;
}

// ---------------------------------------------------------------------------
extern "C" void kernel_launch(void* const* d_in, const int* in_sizes, int n_in,
                              void* d_out, int out_size, void* d_ws, size_t ws_size,
                              hipStream_t stream) {
    const int*   esrc = (const int*)  d_in[0];
    const int*   edst = (const int*)  d_in[1];
    const float* ecut = (const float*)d_in[2];
    const float* einv = (const float*)d_in[3];
    const float* ns   = (const float*)d_in[4];
    const float* nv   = (const float*)d_in[5];
    const float* esh  = (const float*)d_in[6];
    const float* W0   = (const float*)d_in[7];
    const float* W1   = (const float*)d_in[8];
    const float* W2   = (const float*)d_in[9];
    const float* WLs  = (const float*)d_in[10];
    const float* WLv  = (const float*)d_in[11];
    float* out = (float*)d_out;

    const int E  = in_sizes[0];
    const int Nn = in_sizes[4] / S_IN;

    size_t int_bytes = (((size_t)(3 * Nn + 1 + E)) * sizeof(int) + 255) & ~(size_t)255;

    int eblocks = (E + 255) / 256;

    // out is accumulated into by both paths
    hipMemsetAsync(out, 0, (size_t)Nn * OUT_PER_NODE * sizeof(float), stream);

    if (ws_size >= int_bytes + ((size_t)8 << 20)) {
        int*    deg    = (int*)d_ws;
        int*    offs   = deg + Nn;          // Nn+1
        int*    cursor = offs + Nn + 1;     // Nn
        int*    perm   = cursor + Nn;       // E
        __half* gbuf   = (__half*)((char*)d_ws + int_bytes);

        size_t gbuf_avail = ws_size - int_bytes;
        int chunkE = (int)(gbuf_avail / ((size_t)OUT_PER_NODE * sizeof(__half)));
        if (chunkE > E) chunkE = E;

        hipMemsetAsync(deg, 0, (size_t)Nn * sizeof(int), stream);
        hist_kernel<<<eblocks, 256, 0, stream>>>(edst, deg, E);
        scan_kernel<<<1, 1024, 0, stream>>>(deg, offs, cursor, Nn);
        scatter_kernel<<<eblocks, 256, 0, stream>>>(edst, cursor, perm, E);

        int gblocks = (Nn + 3) / 4;   // 4 waves (nodes) per 256-thread block
        for (int p0 = 0; p0 < E; p0 += chunkE) {
            int p1 = p0 + chunkE; if (p1 > E) p1 = E;
            int cblocks = (p1 - p0 + 255) / 256;
            edge_fused<0><<<cblocks, 256, 0, stream>>>(perm, esrc, edst, ecut, einv,
                                                       ns, nv, esh, W0, W1, W2,
                                                       WLs, WLv, gbuf, out, p0, p1);
            gather_sum<<<gblocks, 256, 0, stream>>>(offs, gbuf, out, Nn, p0, p1);
        }
    } else {
        // fallback: per-edge atomics straight into out (no workspace needed)
        edge_fused<1><<<eblocks, 256, 0, stream>>>(nullptr, esrc, edst, ecut, einv,
                                                   ns, nv, esh, W0, W1, W2,
                                                   WLs, WLv, nullptr, out, 0, E);
    }
}

// Round 5
// 853.993 us; speedup vs baseline: 9.3072x; 1.1145x over previous
//
#include <hip/hip_runtime.h>
#include <hip/hip_fp16.h>
#include <math.h>

// Problem constants
constexpr int S_IN = 32, V_IN = 16, INVD = 16;
constexpr int S_MSG = S_IN + V_IN;           // 48
constexpr int V_MSG = S_IN + V_IN;           // 48
constexpr int NFAC  = S_MSG + V_MSG;         // 96
constexpr int S_OUT = 32, V_OUT = 16;
constexpr int OUT_PER_NODE = S_OUT + V_OUT * 3;  // 80
constexpr float ISQRT3 = 0.57735026918962576f;
constexpr float ISQ48  = 0.14433756729740643f;   // 1/sqrt(48)

__device__ __forceinline__ float silu_f(float x) {
    return x / (1.0f + __expf(-x));
}

// ---------------------------------------------------------------------------
// CSR construction
// ---------------------------------------------------------------------------
__global__ __launch_bounds__(256) void hist_kernel(
    const int* __restrict__ edst, int* __restrict__ deg, int E)
{
    int e = blockIdx.x * 256 + threadIdx.x;
    if (e < E) atomicAdd(&deg[edst[e]], 1);
}

__global__ __launch_bounds__(1024) void scan_kernel(
    const int* __restrict__ deg, int* __restrict__ offs,
    int* __restrict__ cursor, int Nn)
{
    const int T = 1024;
    int t = threadIdx.x;
    int chunk = (Nn + T - 1) / T;
    int lo = t * chunk;
    int hi = lo + chunk; if (hi > Nn) hi = Nn;
    int s = 0;
    for (int i = lo; i < hi; i++) s += deg[i];
    __shared__ int ps[T];
    ps[t] = s;
    __syncthreads();
    for (int off = 1; off < T; off <<= 1) {
        int v = (t >= off) ? ps[t - off] : 0;
        __syncthreads();
        ps[t] += v;
        __syncthreads();
    }
    int base = (t > 0) ? ps[t - 1] : 0;
    for (int i = lo; i < hi; i++) {
        offs[i] = base;
        cursor[i] = base;
        base += deg[i];
    }
    if (t == 0) offs[Nn] = ps[T - 1];
}

__global__ __launch_bounds__(256) void scatter_kernel(
    const int* __restrict__ edst, int* __restrict__ cursor,
    int* __restrict__ perm, int E)
{
    int e = blockIdx.x * 256 + threadIdx.x;
    if (e < E) {
        int pos = atomicAdd(&cursor[edst[e]], 1);
        perm[pos] = e;
    }
}

// ---------------------------------------------------------------------------
// Fused edge kernel, phase-structured to avoid register spills.
// ATOMIC=0: write fp16 80-elem row to gbuf at permuted position p.
// ATOMIC=1: atomicAdd fp32 into out (fallback).
// ---------------------------------------------------------------------------
template<int ATOMIC>
__global__ __launch_bounds__(256, 2) void edge_fused(
    const int*   __restrict__ perm,
    const int*   __restrict__ esrc,
    const int*   __restrict__ edst,
    const float* __restrict__ ecut,
    const float* __restrict__ einv,
    const float* __restrict__ ns,
    const float* __restrict__ nv,
    const float* __restrict__ esh,
    const float* __restrict__ W0,
    const float* __restrict__ W1,
    const float* __restrict__ W2,
    const float* __restrict__ WLs,
    const float* __restrict__ WLv,
    __half* __restrict__ gbuf,
    float*  __restrict__ out,
    int p0, int p1)
{
    int p = p0 + blockIdx.x * 256 + threadIdx.x;
    if (p >= p1) return;
    int e = ATOMIC ? p : perm[p];

    constexpr float inv_s0 = 0.25f;   // 1/sqrt(16)
    constexpr float inv_s1 = 0.125f;  // 1/sqrt(64)

    // ---- Phase A: MLP to h2 ----
    float h2[64];
    {
        float x[INVD];
        const float4* xin = reinterpret_cast<const float4*>(einv + (size_t)e * INVD);
        #pragma unroll
        for (int i = 0; i < 4; i++) {
            float4 t = xin[i];
            x[4*i+0] = t.x; x[4*i+1] = t.y; x[4*i+2] = t.z; x[4*i+3] = t.w;
        }
        float h1[64];
        #pragma unroll
        for (int j = 0; j < 64; j++) h1[j] = 0.0f;
        #pragma unroll 4
        for (int i = 0; i < INVD; i++) {
            float xi = x[i];
            #pragma unroll
            for (int j = 0; j < 64; j++)
                h1[j] = fmaf(xi, W0[i*64 + j], h1[j]);
        }
        #pragma unroll
        for (int j = 0; j < 64; j++) h1[j] = silu_f(h1[j] * inv_s0);

        #pragma unroll
        for (int j = 0; j < 64; j++) h2[j] = 0.0f;
        #pragma unroll 4
        for (int k = 0; k < 64; k++) {
            float hk = h1[k];
            #pragma unroll
            for (int j = 0; j < 64; j++)
                h2[j] = fmaf(hk, W1[k*64 + j], h2[j]);
        }
        #pragma unroll
        for (int j = 0; j < 64; j++) h2[j] = silu_f(h2[j] * inv_s1);
    }

    // ---- per-edge small data ----
    int s = esrc[e];
    float K = ecut[e] * inv_s1 * ISQ48;   // folds 1/sqrt(64) and 1/sqrt(48)
    float ev0 = esh[(size_t)e*3 + 0];
    float ev1 = esh[(size_t)e*3 + 1];
    float ev2 = esh[(size_t)e*3 + 2];
    const float* nsrow = ns + (size_t)s * S_IN;
    const float* nvrow = nv + (size_t)s * (V_IN * 3);

    __half* grow = ATOMIC ? nullptr : (gbuf + (size_t)(p - p0) * OUT_PER_NODE);
    float* orow  = ATOMIC ? (out + (size_t)edst[e] * OUT_PER_NODE) : nullptr;

    // ---- Phase B: scalar outputs ys[32], gates chunked 16-wide ----
    {
        float ys[S_OUT];
        #pragma unroll
        for (int o = 0; o < S_OUT; o++) ys[o] = 0.0f;

        #pragma unroll 1
        for (int cc = 0; cc < 48; cc += 16) {
            float fac[16];
            #pragma unroll
            for (int j = 0; j < 16; j++) fac[j] = 0.0f;
            #pragma unroll 4
            for (int k = 0; k < 64; k++) {
                float hk = h2[k];
                #pragma unroll
                for (int j = 0; j < 16; j++)
                    fac[j] = fmaf(hk, W2[k*NFAC + cc + j], fac[j]);
            }
            if (cc == 0) {
                // tp_s rows 0..15: dot(nv row c, ev)/sqrt3
                #pragma unroll
                for (int j = 0; j < 16; j++) {
                    float m = (nvrow[3*j+0]*ev0 + nvrow[3*j+1]*ev1 + nvrow[3*j+2]*ev2)
                              * (ISQRT3 * K) * fac[j];
                    #pragma unroll
                    for (int o = 0; o < S_OUT; o++)
                        ys[o] = fmaf(m, WLs[j*S_OUT + o], ys[o]);
                }
            } else {
                // src_s rows: ns[cc-16+j]
                #pragma unroll
                for (int j = 0; j < 16; j++) {
                    int c = cc + j;               // msg_s row index
                    float m = nsrow[c - V_IN] * K * fac[j];
                    #pragma unroll
                    for (int o = 0; o < S_OUT; o++)
                        ys[o] = fmaf(m, WLs[c*S_OUT + o], ys[o]);
                }
            }
        }

        if (ATOMIC) {
            #pragma unroll
            for (int o = 0; o < S_OUT; o++) atomicAdd(&orow[o], ys[o]);
        } else {
            unsigned int w32[16];
            #pragma unroll
            for (int q = 0; q < 16; q++) {
                __half2 hh = __floats2half2_rn(ys[2*q], ys[2*q+1]);
                w32[q] = *reinterpret_cast<unsigned int*>(&hh);
            }
            uint4* dst = reinterpret_cast<uint4*>(grow);
            #pragma unroll
            for (int q = 0; q < 4; q++)
                dst[q] = make_uint4(w32[4*q+0], w32[4*q+1], w32[4*q+2], w32[4*q+3]);
        }
    }

    // ---- Phase C: vector outputs yv[48], gates chunked 16-wide ----
    {
        float yv[V_OUT * 3];
        #pragma unroll
        for (int q = 0; q < V_OUT*3; q++) yv[q] = 0.0f;

        #pragma unroll 1
        for (int cc = 48; cc < 96; cc += 16) {
            float fac[16];
            #pragma unroll
            for (int j = 0; j < 16; j++) fac[j] = 0.0f;
            #pragma unroll 4
            for (int k = 0; k < 64; k++) {
                float hk = h2[k];
                #pragma unroll
                for (int j = 0; j < 16; j++)
                    fac[j] = fmaf(hk, W2[k*NFAC + cc + j], fac[j]);
            }
            if (cc < 80) {
                // tp_v rows r=cc-48+j in 0..31: ns[r] * ev
                #pragma unroll
                for (int j = 0; j < 16; j++) {
                    int r = cc - 48 + j;
                    float m  = nsrow[r] * K * fac[j];
                    float m0 = m * ev0, m1 = m * ev1, m2 = m * ev2;
                    #pragma unroll
                    for (int o = 0; o < V_OUT; o++) {
                        float w = WLv[r*V_OUT + o];
                        yv[3*o+0] = fmaf(w, m0, yv[3*o+0]);
                        yv[3*o+1] = fmaf(w, m1, yv[3*o+1]);
                        yv[3*o+2] = fmaf(w, m2, yv[3*o+2]);
                    }
                }
            } else {
                // src_v rows r=32..47: nv row (r-32)
                #pragma unroll
                for (int j = 0; j < 16; j++) {
                    int r = 32 + j;
                    float g  = K * fac[j];
                    float v0 = nvrow[3*j+0] * g, v1 = nvrow[3*j+1] * g, v2 = nvrow[3*j+2] * g;
                    #pragma unroll
                    for (int o = 0; o < V_OUT; o++) {
                        float w = WLv[r*V_OUT + o];
                        yv[3*o+0] = fmaf(w, v0, yv[3*o+0]);
                        yv[3*o+1] = fmaf(w, v1, yv[3*o+1]);
                        yv[3*o+2] = fmaf(w, v2, yv[3*o+2]);
                    }
                }
            }
        }

        if (ATOMIC) {
            #pragma unroll
            for (int q = 0; q < V_OUT*3; q++) atomicAdd(&orow[S_OUT + q], yv[q]);
        } else {
            unsigned int w32[24];
            #pragma unroll
            for (int q = 0; q < 24; q++) {
                __half2 hh = __floats2half2_rn(yv[2*q], yv[2*q+1]);
                w32[q] = *reinterpret_cast<unsigned int*>(&hh);
            }
            uint4* dst = reinterpret_cast<uint4*>(grow + S_OUT);
            #pragma unroll
            for (int q = 0; q < 6; q++)
                dst[q] = make_uint4(w32[4*q+0], w32[4*q+1], w32[4*q+2], w32[4*q+3]);
        }
    }
}

// ---------------------------------------------------------------------------
// Gather: one wave per node, sum fp16 rows over the node's permuted range.
// ---------------------------------------------------------------------------
__global__ __launch_bounds__(256) void gather_sum(
    const int*   __restrict__ offs,
    const __half* __restrict__ gbuf,
    float* __restrict__ out,
    int Nn, int p0, int p1)
{
    int wid = (blockIdx.x * 256 + threadIdx.x) >> 6;   // node = global wave id
    int l = threadIdx.x & 63;
    if (wid >= Nn) return;
    int beg = offs[wid], end = offs[wid + 1];
    int lo = beg > p0 ? beg : p0;
    int hi = end < p1 ? end : p1;
    if (lo >= hi) return;

    float a0 = 0.0f, a1 = 0.0f;
    const __half* row = gbuf + (size_t)(lo - p0) * OUT_PER_NODE;
    #pragma unroll 4
    for (int p = lo; p < hi; ++p, row += OUT_PER_NODE) {
        a0 += __half2float(row[l]);
        if (l < 16) a1 += __half2float(row[64 + l]);
    }
    float* orow = out + (size_t)wid * OUT_PER_NODE;
    orow[l] += a0;
    if (l < 16) orow[64 + l] += a1;
}

// ---------------------------------------------------------------------------
extern "C" void kernel_launch(void* const* d_in, const int* in_sizes, int n_in,
                              void* d_out, int out_size, void* d_ws, size_t ws_size,
                              hipStream_t stream) {
    const int*   esrc = (const int*)  d_in[0];
    const int*   edst = (const int*)  d_in[1];
    const float* ecut = (const float*)d_in[2];
    const float* einv = (const float*)d_in[3];
    const float* ns   = (const float*)d_in[4];
    const float* nv   = (const float*)d_in[5];
    const float* esh  = (const float*)d_in[6];
    const float* W0   = (const float*)d_in[7];
    const float* W1   = (const float*)d_in[8];
    const float* W2   = (const float*)d_in[9];
    const float* WLs  = (const float*)d_in[10];
    const float* WLv  = (const float*)d_in[11];
    float* out = (float*)d_out;

    const int E  = in_sizes[0];
    const int Nn = in_sizes[4] / S_IN;

    size_t int_bytes = (((size_t)(3 * Nn + 1 + E)) * sizeof(int) + 255) & ~(size_t)255;

    int eblocks = (E + 255) / 256;

    hipMemsetAsync(out, 0, (size_t)Nn * OUT_PER_NODE * sizeof(float), stream);

    if (ws_size >= int_bytes + ((size_t)8 << 20)) {
        int*    deg    = (int*)d_ws;
        int*    offs   = deg + Nn;          // Nn+1
        int*    cursor = offs + Nn + 1;     // Nn
        int*    perm   = cursor + Nn;       // E
        __half* gbuf   = (__half*)((char*)d_ws + int_bytes);

        size_t gbuf_avail = ws_size - int_bytes;
        int chunkE = (int)(gbuf_avail / ((size_t)OUT_PER_NODE * sizeof(__half)));
        if (chunkE > E) chunkE = E;

        hipMemsetAsync(deg, 0, (size_t)Nn * sizeof(int), stream);
        hist_kernel<<<eblocks, 256, 0, stream>>>(edst, deg, E);
        scan_kernel<<<1, 1024, 0, stream>>>(deg, offs, cursor, Nn);
        scatter_kernel<<<eblocks, 256, 0, stream>>>(edst, cursor, perm, E);

        int gblocks = (Nn + 3) / 4;   // 4 waves (nodes) per 256-thread block
        for (int p0 = 0; p0 < E; p0 += chunkE) {
            int p1 = p0 + chunkE; if (p1 > E) p1 = E;
            int cblocks = (p1 - p0 + 255) / 256;
            edge_fused<0><<<cblocks, 256, 0, stream>>>(perm, esrc, edst, ecut, einv,
                                                       ns, nv, esh, W0, W1, W2,
                                                       WLs, WLv, gbuf, out, p0, p1);
            gather_sum<<<gblocks, 256, 0, stream>>>(offs, gbuf, out, Nn, p0, p1);
        }
    } else {
        edge_fused<1><<<eblocks, 256, 0, stream>>>(nullptr, esrc, edst, ecut, einv,
                                                   ns, nv, esh, W0, W1, W2,
                                                   WLs, WLv, nullptr, out, 0, E);
    }
}